// Round 15
// baseline (241.208 us; speedup 1.0000x reference)
//
#include <hip/hip_runtime.h>

// Problem dims
#define NN 128
#define MM 2048
#define EPSF 0.01f

typedef __bf16 bf16x8 __attribute__((ext_vector_type(8)));
typedef __bf16 bf16x4 __attribute__((ext_vector_type(4)));
typedef float  f32x4  __attribute__((ext_vector_type(4)));

// Workspace layout (float offsets), total 1442944 floats = 5.77 MB.
// Frag-weight arrays live inside the SLACK region (dead before k_main writes).
#define WS_SLACK 0            // [n][m] fp32 (k_main output)
#define WS_WT1F  0            //   bf16 frag-linear Wt1   (32768 fl)
#define WS_WZU1F 32768        //   bf16 frag-linear Wzu1  (32768 fl)
#define WS_WU1F  65536        //   bf16 frag-linear Wu1   (32768 fl)
#define WS_WZU2F 98304        //   bf16 frag-linear Wzu2  (32768 fl)
#define WS_WT0F  131072       //   bf16 frag-linear Wt0   (8192 fl)
#define WS_WU0F  139264       //   bf16 frag-linear Wu0   (8192 fl)
#define WS_XF    147456       //   bf16 frag-linear X     (4096 fl)
#define WS_W2    262144       // [n][256] fp32 gz2*softplus(Wz2)
#define WS_GZ1   294912       // [n][256] fp32
#define WS_YV    327680       // [n][8]  fp32 Y - gy2*Wy2
#define WS_CU2   328704       // [n]     fp32
#define WS_WTF   328832       // bf16 frag-linear softplus(Wz1) [kt][ch][lane][8]
#define WS_A2    361600       // bf16 [2048 m][32] = [U | 1 | 0...]
#define WS_B2    394368       // bf16 [128 n][256 z][32] = [gy0*Wy0 | c0 | 0...]
#define WS_BX    918656       // bf16 [128 n][256 k][32] = [gy1*Wy1 | c1 | 0...]

__device__ __forceinline__ float softplusf(float x) {
    return x > 20.f ? x : log1pf(expf(x));
}

__device__ __forceinline__ bf16x8 ld_cvt8(const float* __restrict__ p) {
    const float4* p4 = (const float4*)p;
    float4 a = p4[0], b = p4[1];
    bf16x8 r;
    r[0] = (__bf16)a.x; r[1] = (__bf16)a.y; r[2] = (__bf16)a.z; r[3] = (__bf16)a.w;
    r[4] = (__bf16)b.x; r[5] = (__bf16)b.y; r[6] = (__bf16)b.z; r[7] = (__bf16)b.w;
    return r;
}

// frag-linear converter: dst elem o = ((ot*CH + ch)*64 + lane)*8 + j
// src = W[(ot*16 + c)*K + ch*32 + q*8 + j], K = CH*32.
template<int CH, bool SP>
__device__ __forceinline__ void frag_cvt(const float* __restrict__ W,
                                         __bf16* __restrict__ F, int o) {
    const int j0 = o & 7;
    const int lane = (o >> 3) & 63;
    const int c = lane & 15, q = lane >> 4;
    const int ch = (o >> 9) & (CH - 1);
    const int ot = o >> (CH == 8 ? 12 : 10);
    const float* src = W + (ot * 16 + c) * (CH * 32) + ch * 32 + q * 8 + j0;
    float4 v = *(const float4*)src;
    bf16x4 r;
    if (SP) {
        r[0] = (__bf16)softplusf(v.x); r[1] = (__bf16)softplusf(v.y);
        r[2] = (__bf16)softplusf(v.z); r[3] = (__bf16)softplusf(v.w);
    } else {
        r[0] = (__bf16)v.x; r[1] = (__bf16)v.y;
        r[2] = (__bf16)v.z; r[3] = (__bf16)v.w;
    }
    *(bf16x4*)(F + o) = r;
}

// ---------------------------------------------------------------------------
// k_wprep: all weight->bf16 fragment-linear conversions + A2. 424 blocks.
// ---------------------------------------------------------------------------
__global__ __launch_bounds__(256) void k_wprep(
    const float* __restrict__ X, const float* __restrict__ U,
    const float* __restrict__ Wt0, const float* __restrict__ Wu0,
    const float* __restrict__ Wt1, const float* __restrict__ Wzu1,
    const float* __restrict__ Wu1, const float* __restrict__ Wzu2,
    const float* __restrict__ Wz1,
    float* __restrict__ ws)
{
    const int b = blockIdx.x, t = threadIdx.x;
    if (b < 64) {
        frag_cvt<8, true>(Wz1, (__bf16*)(ws + WS_WTF), b * 1024 + t * 4);
    } else if (b < 128) {
        const int i = (b - 64) * 1024 + t * 4;
        const int m = i >> 5, cc = i & 31;
        bf16x4 r;
        if (cc < 8) {
            float4 u = *(const float4*)(U + m * 8 + cc);
            r[0] = (__bf16)u.x; r[1] = (__bf16)u.y;
            r[2] = (__bf16)u.z; r[3] = (__bf16)u.w;
        } else if (cc == 8) {
            r[0] = (__bf16)1.f; r[1] = (__bf16)0.f; r[2] = (__bf16)0.f; r[3] = (__bf16)0.f;
        } else {
            r[0] = (__bf16)0.f; r[1] = (__bf16)0.f; r[2] = (__bf16)0.f; r[3] = (__bf16)0.f;
        }
        *(bf16x4*)((__bf16*)(ws + WS_A2) + i) = r;
    } else if (b < 192) {
        frag_cvt<8, false>(Wt1, (__bf16*)(ws + WS_WT1F), (b - 128) * 1024 + t * 4);
    } else if (b < 256) {
        frag_cvt<8, false>(Wzu1, (__bf16*)(ws + WS_WZU1F), (b - 192) * 1024 + t * 4);
    } else if (b < 320) {
        frag_cvt<8, false>(Wu1, (__bf16*)(ws + WS_WU1F), (b - 256) * 1024 + t * 4);
    } else if (b < 384) {
        frag_cvt<8, false>(Wzu2, (__bf16*)(ws + WS_WZU2F), (b - 320) * 1024 + t * 4);
    } else if (b < 400) {
        frag_cvt<2, false>(Wt0, (__bf16*)(ws + WS_WT0F), (b - 384) * 1024 + t * 4);
    } else if (b < 416) {
        frag_cvt<2, false>(Wu0, (__bf16*)(ws + WS_WU0F), (b - 400) * 1024 + t * 4);
    } else {
        frag_cvt<2, false>(X, (__bf16*)(ws + WS_XF), (b - 416) * 1024 + t * 4);
    }
}

// ---------------------------------------------------------------------------
// k_ctx: context path, 32 blocks x 512 threads. block = (n-group g, quarter s).
// Redundant u1/u2 in LDS; exclusive col-quarter of c0/gz1/c1/w2 + B2/BX
// z-quarter; yv/cu2 on (s==0, wave 4). Frag-linear weight loads throughout.
// ---------------------------------------------------------------------------
__global__ __launch_bounds__(512) void k_ctx(
    const float* __restrict__ Y,
    const float* __restrict__ bt0, const float* __restrict__ b0,
    const float* __restrict__ Wyu0, const float* __restrict__ byu0,
    const float* __restrict__ Wy0,
    const float* __restrict__ bt1, const float* __restrict__ bzu1,
    const float* __restrict__ Wyu1, const float* __restrict__ byu1,
    const float* __restrict__ Wy1,
    const float* __restrict__ b1,
    const float* __restrict__ bzu2, const float* __restrict__ Wz2,
    const float* __restrict__ Wyu2, const float* __restrict__ byu2,
    const float* __restrict__ Wy2,
    const float* __restrict__ Wu2, const float* __restrict__ b2,
    float* __restrict__ ws)
{
    __shared__ __bf16 u1b[16][264];
    __shared__ __bf16 u2b[16][264];
    __shared__ __bf16 c0q[16][64];
    __shared__ __bf16 c1q[16][64];
    __shared__ float gy0s[16][8];
    __shared__ float gy1s[16][8];

    const int t = threadIdx.x, b = blockIdx.x;
    const int w = t >> 6, lane = t & 63;
    const int c = lane & 15, q = lane >> 4;
    const int g = b >> 2, s = b & 3;
    const int nb = g * 16;

    const __bf16* Xf    = (const __bf16*)(ws + WS_XF);
    const __bf16* Wt0f  = (const __bf16*)(ws + WS_WT0F);
    const __bf16* Wu0f  = (const __bf16*)(ws + WS_WU0F);
    const __bf16* Wt1f  = (const __bf16*)(ws + WS_WT1F);
    const __bf16* Wzu1f = (const __bf16*)(ws + WS_WZU1F);
    const __bf16* Wu1f  = (const __bf16*)(ws + WS_WU1F);
    const __bf16* Wzu2f = (const __bf16*)(ws + WS_WZU2F);

    // ======== Phase A: level 1 (K=64 over X) ========
    bf16x8 a1[2];
#pragma unroll
    for (int ch = 0; ch < 2; ++ch)
        a1[ch] = *(const bf16x8*)(Xf + ((g * 2 + ch) * 64 + lane) * 8);

    for (int tt = w; tt < 16; tt += 8) {   // u1 full
        f32x4 D = {0.f, 0.f, 0.f, 0.f};
#pragma unroll
        for (int ch = 0; ch < 2; ++ch) {
            bf16x8 bb = *(const bf16x8*)(Wt0f + ((tt * 2 + ch) * 64 + lane) * 8);
            D = __builtin_amdgcn_mfma_f32_16x16x32_bf16(a1[ch], bb, D, 0, 0, 0);
        }
        const float bv = bt0[tt * 16 + c];
#pragma unroll
        for (int r = 0; r < 4; ++r)
            u1b[4 * q + r][tt * 16 + c] = (__bf16)fmaxf(D[r] + bv, 0.f);
    }
    if (w < 4) {   // c0 quarter
        const int ot = 4 * s + w;
        f32x4 D = {0.f, 0.f, 0.f, 0.f};
#pragma unroll
        for (int ch = 0; ch < 2; ++ch) {
            bf16x8 bb = *(const bf16x8*)(Wu0f + ((ot * 2 + ch) * 64 + lane) * 8);
            D = __builtin_amdgcn_mfma_f32_16x16x32_bf16(a1[ch], bb, D, 0, 0, 0);
        }
        const float bv = b0[ot * 16 + c];
#pragma unroll
        for (int r = 0; r < 4; ++r)
            c0q[4 * q + r][w * 16 + c] = (__bf16)(D[r] + bv);
    } else if (w == 4) {   // gy0
        const float* rp = Wyu0 + (c & 7) * 64;
        f32x4 D = {0.f, 0.f, 0.f, 0.f};
#pragma unroll
        for (int ch = 0; ch < 2; ++ch) {
            bf16x8 bb = ld_cvt8(rp + ch * 32 + q * 8);
            D = __builtin_amdgcn_mfma_f32_16x16x32_bf16(a1[ch], bb, D, 0, 0, 0);
        }
        if (c < 8) {
            const float bv = byu0[c];
#pragma unroll
            for (int r = 0; r < 4; ++r)
                gy0s[4 * q + r][c] = D[r] + bv;
        }
    }
    __syncthreads();

    // ======== Phase B: level 2 (K=256 over u1) ========
    bf16x8 aF[8];
#pragma unroll
    for (int ch = 0; ch < 8; ++ch)
        aF[ch] = *(const bf16x8*)&u1b[c][ch * 32 + q * 8];

    for (int tt = w; tt < 16; tt += 8) {   // u2 full
        f32x4 D = {0.f, 0.f, 0.f, 0.f};
#pragma unroll
        for (int ch = 0; ch < 8; ++ch) {
            bf16x8 bb = *(const bf16x8*)(Wt1f + ((tt * 8 + ch) * 64 + lane) * 8);
            D = __builtin_amdgcn_mfma_f32_16x16x32_bf16(aF[ch], bb, D, 0, 0, 0);
        }
        const float bv = bt1[tt * 16 + c];
#pragma unroll
        for (int r = 0; r < 4; ++r)
            u2b[4 * q + r][tt * 16 + c] = (__bf16)fmaxf(D[r] + bv, 0.f);
    }
    if (w < 4) {   // gz1 quarter -> global
        const int ot = 4 * s + w, col = ot * 16 + c;
        f32x4 D = {0.f, 0.f, 0.f, 0.f};
#pragma unroll
        for (int ch = 0; ch < 8; ++ch) {
            bf16x8 bb = *(const bf16x8*)(Wzu1f + ((ot * 8 + ch) * 64 + lane) * 8);
            D = __builtin_amdgcn_mfma_f32_16x16x32_bf16(aF[ch], bb, D, 0, 0, 0);
        }
        const float bv = bzu1[col];
#pragma unroll
        for (int r = 0; r < 4; ++r)
            ws[WS_GZ1 + (nb + 4 * q + r) * 256 + col] = fmaxf(D[r] + bv, 0.f);
    } else {       // c1 quarter -> LDS
        const int ot = 4 * s + (w - 4);
        f32x4 D = {0.f, 0.f, 0.f, 0.f};
#pragma unroll
        for (int ch = 0; ch < 8; ++ch) {
            bf16x8 bb = *(const bf16x8*)(Wu1f + ((ot * 8 + ch) * 64 + lane) * 8);
            D = __builtin_amdgcn_mfma_f32_16x16x32_bf16(aF[ch], bb, D, 0, 0, 0);
        }
        const float bv = b1[ot * 16 + c];
#pragma unroll
        for (int r = 0; r < 4; ++r)
            c1q[4 * q + r][(w - 4) * 16 + c] = (__bf16)(D[r] + bv);
    }
    if (w == 0) {  // gy1
        const float* rp = Wyu1 + (c & 7) * 256;
        f32x4 D = {0.f, 0.f, 0.f, 0.f};
#pragma unroll
        for (int ch = 0; ch < 8; ++ch) {
            bf16x8 bb = ld_cvt8(rp + ch * 32 + q * 8);
            D = __builtin_amdgcn_mfma_f32_16x16x32_bf16(aF[ch], bb, D, 0, 0, 0);
        }
        if (c < 8) {
            const float bv = byu1[c];
#pragma unroll
            for (int r = 0; r < 4; ++r)
                gy1s[4 * q + r][c] = D[r] + bv;
        }
    }
    __syncthreads();

    // ======== Phase C: level 3 (K=256 over u2) + yv/cu2 + B2/BX ========
    bf16x8 aG[8];
#pragma unroll
    for (int ch = 0; ch < 8; ++ch)
        aG[ch] = *(const bf16x8*)&u2b[c][ch * 32 + q * 8];

    if (w < 4) {   // w2 quarter -> global
        const int ot = 4 * s + w, col = ot * 16 + c;
        f32x4 D = {0.f, 0.f, 0.f, 0.f};
#pragma unroll
        for (int ch = 0; ch < 8; ++ch) {
            bf16x8 bb = *(const bf16x8*)(Wzu2f + ((ot * 8 + ch) * 64 + lane) * 8);
            D = __builtin_amdgcn_mfma_f32_16x16x32_bf16(aG[ch], bb, D, 0, 0, 0);
        }
        const float bv = bzu2[col];
        const float sp = softplusf(Wz2[col]);
#pragma unroll
        for (int r = 0; r < 4; ++r) {
            float gz2 = fmaxf(D[r] + bv, 0.f);
            ws[WS_W2 + (nb + 4 * q + r) * 256 + col] = gz2 * sp;
        }
    } else if (w == 4 && s == 0) {   // yv (c<8) / cu2 (c==8)
        const float* rp = (c < 8) ? (Wyu2 + c * 256) : Wu2;
        f32x4 D = {0.f, 0.f, 0.f, 0.f};
#pragma unroll
        for (int ch = 0; ch < 8; ++ch) {
            bf16x8 bb = ld_cvt8(rp + ch * 32 + q * 8);
            D = __builtin_amdgcn_mfma_f32_16x16x32_bf16(aG[ch], bb, D, 0, 0, 0);
        }
        if (c < 8) {
            const float bv = byu2[c];
            const float wy2 = Wy2[c];
#pragma unroll
            for (int r = 0; r < 4; ++r) {
                const int n = nb + 4 * q + r;
                ws[WS_YV + n * 8 + c] = Y[n * 8 + c] - (D[r] + bv) * wy2;
            }
        } else if (c == 8) {
#pragma unroll
            for (int r = 0; r < 4; ++r)
                ws[WS_CU2 + nb + 4 * q + r] = D[r] + b2[0];
        }
    }

    // B2/BX materialization for this block's (n-group, z-quarter)
    {
        bf16x8 zz;
#pragma unroll
        for (int j = 0; j < 8; ++j) zz[j] = (__bf16)0.f;
#pragma unroll
        for (int j = 0; j < 2; ++j) {
            const int idx = j * 512 + t;
            const int zl = idx & 63, nl = idx >> 6;
            const int z = 64 * s + zl, n = nb + nl;
            {   // B2
                const float* wy = Wy0 + z * 8;
                __bf16* dst = (__bf16*)(ws + WS_B2) + (n * 256 + z) * 32;
                bf16x8 v0, v1 = zz;
#pragma unroll
                for (int d = 0; d < 8; ++d) v0[d] = (__bf16)(gy0s[nl][d] * wy[d]);
                v1[0] = c0q[nl][zl];
                *(bf16x8*)(dst)      = v0;
                *(bf16x8*)(dst + 8)  = v1;
                *(bf16x8*)(dst + 16) = zz;
                *(bf16x8*)(dst + 24) = zz;
            }
            {   // BX
                const float* wy = Wy1 + z * 8;
                __bf16* dst = (__bf16*)(ws + WS_BX) + (n * 256 + z) * 32;
                bf16x8 v0, v1 = zz;
#pragma unroll
                for (int d = 0; d < 8; ++d) v0[d] = (__bf16)(gy1s[nl][d] * wy[d]);
                v1[0] = c1q[nl][zl];
                *(bf16x8*)(dst)      = v0;
                *(bf16x8*)(dst + 8)  = v1;
                *(bf16x8*)(dst + 16) = zz;
                *(bf16x8*)(dst + 24) = zz;
            }
        }
    }
}

// ---------------------------------------------------------------------------
// k_main: R8 structure + s-loop over two 64-m subtiles per block (R2's proven
// barrier scheme) — halves WTF L2 traffic. Grid (16, 128) = 2048 blocks.
// ---------------------------------------------------------------------------
__global__ __launch_bounds__(256, 4) void k_main(
    const float* __restrict__ U,
    float* __restrict__ ws)
{
    __shared__ __bf16 zh[64][264];
    __shared__ float gz1s[256];
    __shared__ float w2s[256];
    __shared__ float psum[4][64];

    const int t  = threadIdx.x;
    const int n  = blockIdx.y;
    const int mp = blockIdx.x;
    const int w    = t >> 6;
    const int lane = t & 63;
    const int c = lane & 15;
    const int q = lane >> 4;

    gz1s[t] = ws[WS_GZ1 + n * 256 + t];
    w2s[t]  = ws[WS_W2  + n * 256 + t];
    const float cu2 = ws[WS_CU2 + n];

    const __bf16* A2p = (const __bf16*)(ws + WS_A2);
    const __bf16* B2p = (const __bf16*)(ws + WS_B2) + n * 8192;
    const __bf16* BXp = (const __bf16*)(ws + WS_BX) + n * 8192;
    const __bf16* WTF = (const __bf16*)(ws + WS_WTF);

    // B2 fragments are s-invariant: load once
    bf16x8 b2f[4];
#pragma unroll
    for (int zt = 0; zt < 4; ++zt)
        b2f[zt] = *(const bf16x8*)(B2p + (64 * w + 16 * zt + c) * 32 + q * 8);
    bf16x8 bx[4];
#pragma unroll
    for (int kj = 0; kj < 4; ++kj)
        bx[kj] = *(const bf16x8*)(BXp + (64 * w + 16 * kj + c) * 32 + q * 8);

#pragma unroll 1
    for (int s = 0; s < 2; ++s) {
        const int m0 = mp * 128 + s * 64;

        bf16x8 a2f[4];
#pragma unroll
        for (int mi = 0; mi < 4; ++mi)
            a2f[mi] = *(const bf16x8*)(A2p + (m0 + 16 * mi + c) * 32 + q * 8);

        // ---- pre-GEMM: D1[z][m], wave w covers z in [64w, 64w+64) ----
        {
            f32x4 pre[4][4];
#pragma unroll
            for (int zt = 0; zt < 4; ++zt)
#pragma unroll
                for (int mi = 0; mi < 4; ++mi) {
                    f32x4 zacc = {0.f, 0.f, 0.f, 0.f};
                    pre[zt][mi] = __builtin_amdgcn_mfma_f32_16x16x32_bf16(
                        b2f[zt], a2f[mi], zacc, 0, 0, 0);
                }
#pragma unroll
            for (int zt = 0; zt < 4; ++zt) {
                const int zb = 64 * w + 16 * zt + 4 * q;
#pragma unroll
                for (int mi = 0; mi < 4; ++mi) {
                    bf16x4 v4;
#pragma unroll
                    for (int r = 0; r < 4; ++r)
                        v4[r] = (__bf16)(fmaxf(pre[zt][mi][r], 0.f) * gz1s[zb + r]);
                    *(bf16x4*)&zh[c + 16 * mi][zb] = v4;
                }
            }
        }

        f32x4 acc[4][4];
#pragma unroll
        for (int mi = 0; mi < 4; ++mi)
#pragma unroll
            for (int kj = 0; kj < 4; ++kj)
                acc[mi][kj] = f32x4{0.f, 0.f, 0.f, 0.f};

        __syncthreads();   // zh ready

        for (int ch = 0; ch < 8; ++ch) {
            bf16x8 az[4], bw[4];
#pragma unroll
            for (int mi = 0; mi < 4; ++mi)
                az[mi] = *(const bf16x8*)&zh[c + 16 * mi][ch * 32 + q * 8];
#pragma unroll
            for (int kj = 0; kj < 4; ++kj)
                bw[kj] = *(const bf16x8*)(WTF + ((4 * w + kj) * 8 + ch) * 512 + lane * 8);
#pragma unroll
            for (int mi = 0; mi < 4; ++mi)
#pragma unroll
                for (int kj = 0; kj < 4; ++kj)
                    acc[mi][kj] = __builtin_amdgcn_mfma_f32_16x16x32_bf16(
                        az[mi], bw[kj], acc[mi][kj], 0, 0, 0);
        }
        // rank-1 chunk: [U|1] x [gy1*Wy1 | c1]
#pragma unroll
        for (int mi = 0; mi < 4; ++mi)
#pragma unroll
            for (int kj = 0; kj < 4; ++kj)
                acc[mi][kj] = __builtin_amdgcn_mfma_f32_16x16x32_bf16(
                    a2f[mi], bx[kj], acc[mi][kj], 0, 0, 0);

        // ---- epilogue ----
        float p[4][4];
#pragma unroll
        for (int mi = 0; mi < 4; ++mi)
#pragma unroll
            for (int r = 0; r < 4; ++r) p[mi][r] = 0.f;
#pragma unroll
        for (int kj = 0; kj < 4; ++kj) {
            float w2v = w2s[64 * w + 16 * kj + c];
#pragma unroll
            for (int mi = 0; mi < 4; ++mi)
#pragma unroll
                for (int r = 0; r < 4; ++r)
                    p[mi][r] += fmaxf(acc[mi][kj][r], 0.f) * w2v;
        }
#pragma unroll
        for (int mi = 0; mi < 4; ++mi)
#pragma unroll
            for (int r = 0; r < 4; ++r) {
                float v = p[mi][r];
                v += __shfl_xor(v, 8);
                v += __shfl_xor(v, 4);
                v += __shfl_xor(v, 2);
                v += __shfl_xor(v, 1);
                p[mi][r] = v;
            }
        if (c == 0) {
#pragma unroll
            for (int mi = 0; mi < 4; ++mi)
                *(float4*)&psum[w][16 * mi + 4 * q] =
                    make_float4(p[mi][0], p[mi][1], p[mi][2], p[mi][3]);
        }
        __syncthreads();   // psum ready; all zh reads done -> safe to rewrite
        if (t < 64) {
            float sd = 0.f;
            const float* urow = U + (m0 + t) * 8;
#pragma unroll
            for (int d = 0; d < 8; ++d) sd += urow[d] * ws[WS_YV + n * 8 + d];
            float pp = psum[0][t] + psum[1][t] + psum[2][t] + psum[3][t];
            ws[WS_SLACK + n * 2048 + m0 + t] = sd - cu2 - pp;
        }
    }
}

// ---------------------------------------------------------------------------
// k_lse: per-n stable logsumexp over m -> psi[n]
// ---------------------------------------------------------------------------
__global__ __launch_bounds__(256) void k_lse(const float* __restrict__ ws,
                                             float* __restrict__ out) {
    __shared__ float redmax[4];
    __shared__ float redsum[4];
    const int n = blockIdx.x;
    const int t = threadIdx.x;
    const float* s = ws + WS_SLACK + n * 2048;

    float vals[8];
    float mx = -3.4e38f;
#pragma unroll
    for (int i = 0; i < 8; ++i) {
        vals[i] = s[t + 256 * i];
        mx = fmaxf(mx, vals[i]);
    }
#pragma unroll
    for (int off = 32; off; off >>= 1) mx = fmaxf(mx, __shfl_xor(mx, off));
    if ((t & 63) == 0) redmax[t >> 6] = mx;
    __syncthreads();
    mx = fmaxf(fmaxf(redmax[0], redmax[1]), fmaxf(redmax[2], redmax[3]));

    float sum = 0.f;
#pragma unroll
    for (int i = 0; i < 8; ++i) sum += expf((vals[i] - mx) * (1.f / EPSF));
#pragma unroll
    for (int off = 32; off; off >>= 1) sum += __shfl_xor(sum, off);
    if ((t & 63) == 0) redsum[t >> 6] = sum;
    __syncthreads();
    if (t == 0) {
        float S = redsum[0] + redsum[1] + redsum[2] + redsum[3];
        out[n] = EPSF * logf(S * (1.f / 2048.f)) + mx;
    }
}

// ---------------------------------------------------------------------------
extern "C" void kernel_launch(void* const* d_in, const int* in_sizes, int n_in,
                              void* d_out, int out_size, void* d_ws, size_t ws_size,
                              hipStream_t stream) {
    const float* X    = (const float*)d_in[0];
    const float* Uu   = (const float*)d_in[1];
    const float* Yy   = (const float*)d_in[2];
    const float* Wt0  = (const float*)d_in[3];
    const float* bt0  = (const float*)d_in[4];
    const float* Wt1  = (const float*)d_in[5];
    const float* bt1  = (const float*)d_in[6];
    const float* Wyu0 = (const float*)d_in[7];
    const float* byu0 = (const float*)d_in[8];
    const float* Wy0  = (const float*)d_in[9];
    const float* Wu0  = (const float*)d_in[10];
    const float* b0   = (const float*)d_in[11];
    const float* Wzu1 = (const float*)d_in[12];
    const float* bzu1 = (const float*)d_in[13];
    const float* Wz1  = (const float*)d_in[14];
    const float* Wyu1 = (const float*)d_in[15];
    const float* byu1 = (const float*)d_in[16];
    const float* Wy1  = (const float*)d_in[17];
    const float* Wu1  = (const float*)d_in[18];
    const float* b1   = (const float*)d_in[19];
    const float* Wzu2 = (const float*)d_in[20];
    const float* bzu2 = (const float*)d_in[21];
    const float* Wz2  = (const float*)d_in[22];
    const float* Wyu2 = (const float*)d_in[23];
    const float* byu2 = (const float*)d_in[24];
    const float* Wy2  = (const float*)d_in[25];
    const float* Wu2  = (const float*)d_in[26];
    const float* b2   = (const float*)d_in[27];
    float* ws  = (float*)d_ws;
    float* out = (float*)d_out;

    k_wprep<<<dim3(424), dim3(256), 0, stream>>>(
        X, Uu, Wt0, Wu0, Wt1, Wzu1, Wu1, Wzu2, Wz1, ws);
    k_ctx<<<dim3(32), dim3(512), 0, stream>>>(
        Yy, bt0, b0, Wyu0, byu0, Wy0, bt1, bzu1, Wyu1, byu1, Wy1, b1,
        bzu2, Wz2, Wyu2, byu2, Wy2, Wu2, b2, ws);
    k_main<<<dim3(16, NN), dim3(256), 0, stream>>>(Uu, ws);
    k_lse<<<dim3(128), dim3(256), 0, stream>>>(ws, out);
}

// Round 17
// 172.537 us; speedup vs baseline: 1.3980x; 1.3980x over previous
//
#include <hip/hip_runtime.h>

// Problem dims
#define NN 128
#define MM 2048
#define EPSF 0.01f

typedef __bf16 bf16x8 __attribute__((ext_vector_type(8)));
typedef __bf16 bf16x4 __attribute__((ext_vector_type(4)));
typedef float  f32x4  __attribute__((ext_vector_type(4)));

// Workspace layout (float offsets), total 1442944 floats = 5.77 MB.
// Frag-weight arrays live inside the SLACK region (dead before k_main writes).
#define WS_SLACK 0            // [n][m] fp32 (k_main output)
#define WS_WT1F  0            //   bf16 frag-linear Wt1   (32768 fl)
#define WS_WZU1F 32768        //   bf16 frag-linear Wzu1  (32768 fl)
#define WS_WU1F  65536        //   bf16 frag-linear Wu1   (32768 fl)
#define WS_WZU2F 98304        //   bf16 frag-linear Wzu2  (32768 fl)
#define WS_WT0F  131072       //   bf16 frag-linear Wt0   (8192 fl)
#define WS_WU0F  139264       //   bf16 frag-linear Wu0   (8192 fl)
#define WS_XF    147456       //   bf16 frag-linear X     (4096 fl)
#define WS_W2    262144       // [n][256] fp32 gz2*softplus(Wz2)
#define WS_GZ1   294912       // [n][256] fp32
#define WS_YV    327680       // [n][8]  fp32 Y - gy2*Wy2
#define WS_CU2   328704       // [n]     fp32
#define WS_WTF   328832       // bf16 frag-linear softplus(Wz1) [kt][ch][lane][8]
#define WS_A2    361600       // bf16 [2048 m][32] = [U | 1 | 0...]
#define WS_B2    394368       // bf16 [128 n][256 z][32] = [gy0*Wy0 | c0 | 0...]
#define WS_BX    918656       // bf16 [128 n][256 k][32] = [gy1*Wy1 | c1 | 0...]

__device__ __forceinline__ float softplusf(float x) {
    return x > 20.f ? x : log1pf(expf(x));
}

__device__ __forceinline__ bf16x8 ld_cvt8(const float* __restrict__ p) {
    const float4* p4 = (const float4*)p;
    float4 a = p4[0], b = p4[1];
    bf16x8 r;
    r[0] = (__bf16)a.x; r[1] = (__bf16)a.y; r[2] = (__bf16)a.z; r[3] = (__bf16)a.w;
    r[4] = (__bf16)b.x; r[5] = (__bf16)b.y; r[6] = (__bf16)b.z; r[7] = (__bf16)b.w;
    return r;
}

// frag-linear converter: dst elem o = ((ot*CH + ch)*64 + lane)*8 + j
// src = W[(ot*16 + c)*K + ch*32 + q*8 + j], K = CH*32.
template<int CH, bool SP>
__device__ __forceinline__ void frag_cvt(const float* __restrict__ W,
                                         __bf16* __restrict__ F, int o) {
    const int j0 = o & 7;
    const int lane = (o >> 3) & 63;
    const int c = lane & 15, q = lane >> 4;
    const int ch = (o >> 9) & (CH - 1);
    const int ot = o >> (CH == 8 ? 12 : 10);
    const float* src = W + (ot * 16 + c) * (CH * 32) + ch * 32 + q * 8 + j0;
    float4 v = *(const float4*)src;
    bf16x4 r;
    if (SP) {
        r[0] = (__bf16)softplusf(v.x); r[1] = (__bf16)softplusf(v.y);
        r[2] = (__bf16)softplusf(v.z); r[3] = (__bf16)softplusf(v.w);
    } else {
        r[0] = (__bf16)v.x; r[1] = (__bf16)v.y;
        r[2] = (__bf16)v.z; r[3] = (__bf16)v.w;
    }
    *(bf16x4*)(F + o) = r;
}

// ---------------------------------------------------------------------------
// k_wprep: all weight->bf16 fragment-linear conversions + A2. 424 blocks.
// ---------------------------------------------------------------------------
__global__ __launch_bounds__(256) void k_wprep(
    const float* __restrict__ X, const float* __restrict__ U,
    const float* __restrict__ Wt0, const float* __restrict__ Wu0,
    const float* __restrict__ Wt1, const float* __restrict__ Wzu1,
    const float* __restrict__ Wu1, const float* __restrict__ Wzu2,
    const float* __restrict__ Wz1,
    float* __restrict__ ws)
{
    const int b = blockIdx.x, t = threadIdx.x;
    if (b < 64) {
        frag_cvt<8, true>(Wz1, (__bf16*)(ws + WS_WTF), b * 1024 + t * 4);
    } else if (b < 128) {
        const int i = (b - 64) * 1024 + t * 4;
        const int m = i >> 5, cc = i & 31;
        bf16x4 r;
        if (cc < 8) {
            float4 u = *(const float4*)(U + m * 8 + cc);
            r[0] = (__bf16)u.x; r[1] = (__bf16)u.y;
            r[2] = (__bf16)u.z; r[3] = (__bf16)u.w;
        } else if (cc == 8) {
            r[0] = (__bf16)1.f; r[1] = (__bf16)0.f; r[2] = (__bf16)0.f; r[3] = (__bf16)0.f;
        } else {
            r[0] = (__bf16)0.f; r[1] = (__bf16)0.f; r[2] = (__bf16)0.f; r[3] = (__bf16)0.f;
        }
        *(bf16x4*)((__bf16*)(ws + WS_A2) + i) = r;
    } else if (b < 192) {
        frag_cvt<8, false>(Wt1, (__bf16*)(ws + WS_WT1F), (b - 128) * 1024 + t * 4);
    } else if (b < 256) {
        frag_cvt<8, false>(Wzu1, (__bf16*)(ws + WS_WZU1F), (b - 192) * 1024 + t * 4);
    } else if (b < 320) {
        frag_cvt<8, false>(Wu1, (__bf16*)(ws + WS_WU1F), (b - 256) * 1024 + t * 4);
    } else if (b < 384) {
        frag_cvt<8, false>(Wzu2, (__bf16*)(ws + WS_WZU2F), (b - 320) * 1024 + t * 4);
    } else if (b < 400) {
        frag_cvt<2, false>(Wt0, (__bf16*)(ws + WS_WT0F), (b - 384) * 1024 + t * 4);
    } else if (b < 416) {
        frag_cvt<2, false>(Wu0, (__bf16*)(ws + WS_WU0F), (b - 400) * 1024 + t * 4);
    } else {
        frag_cvt<2, false>(X, (__bf16*)(ws + WS_XF), (b - 416) * 1024 + t * 4);
    }
}

// ---------------------------------------------------------------------------
// k_ctx: context path, 32 blocks x 512 threads. block = (n-group g, quarter s).
// Redundant u1/u2 in LDS; exclusive col-quarter of c0/gz1/c1/w2 + B2/BX
// z-quarter; yv/cu2 on (s==0, wave 4). Frag-linear weight loads throughout.
// ---------------------------------------------------------------------------
__global__ __launch_bounds__(512) void k_ctx(
    const float* __restrict__ Y,
    const float* __restrict__ bt0, const float* __restrict__ b0,
    const float* __restrict__ Wyu0, const float* __restrict__ byu0,
    const float* __restrict__ Wy0,
    const float* __restrict__ bt1, const float* __restrict__ bzu1,
    const float* __restrict__ Wyu1, const float* __restrict__ byu1,
    const float* __restrict__ Wy1,
    const float* __restrict__ b1,
    const float* __restrict__ bzu2, const float* __restrict__ Wz2,
    const float* __restrict__ Wyu2, const float* __restrict__ byu2,
    const float* __restrict__ Wy2,
    const float* __restrict__ Wu2, const float* __restrict__ b2,
    float* __restrict__ ws)
{
    __shared__ __bf16 u1b[16][264];
    __shared__ __bf16 u2b[16][264];
    __shared__ __bf16 c0q[16][64];
    __shared__ __bf16 c1q[16][64];
    __shared__ float gy0s[16][8];
    __shared__ float gy1s[16][8];

    const int t = threadIdx.x, b = blockIdx.x;
    const int w = t >> 6, lane = t & 63;
    const int c = lane & 15, q = lane >> 4;
    const int g = b >> 2, s = b & 3;
    const int nb = g * 16;

    const __bf16* Xf    = (const __bf16*)(ws + WS_XF);
    const __bf16* Wt0f  = (const __bf16*)(ws + WS_WT0F);
    const __bf16* Wu0f  = (const __bf16*)(ws + WS_WU0F);
    const __bf16* Wt1f  = (const __bf16*)(ws + WS_WT1F);
    const __bf16* Wzu1f = (const __bf16*)(ws + WS_WZU1F);
    const __bf16* Wu1f  = (const __bf16*)(ws + WS_WU1F);
    const __bf16* Wzu2f = (const __bf16*)(ws + WS_WZU2F);

    // ======== Phase A: level 1 (K=64 over X) ========
    bf16x8 a1[2];
#pragma unroll
    for (int ch = 0; ch < 2; ++ch)
        a1[ch] = *(const bf16x8*)(Xf + ((g * 2 + ch) * 64 + lane) * 8);

    for (int tt = w; tt < 16; tt += 8) {   // u1 full
        f32x4 D = {0.f, 0.f, 0.f, 0.f};
#pragma unroll
        for (int ch = 0; ch < 2; ++ch) {
            bf16x8 bb = *(const bf16x8*)(Wt0f + ((tt * 2 + ch) * 64 + lane) * 8);
            D = __builtin_amdgcn_mfma_f32_16x16x32_bf16(a1[ch], bb, D, 0, 0, 0);
        }
        const float bv = bt0[tt * 16 + c];
#pragma unroll
        for (int r = 0; r < 4; ++r)
            u1b[4 * q + r][tt * 16 + c] = (__bf16)fmaxf(D[r] + bv, 0.f);
    }
    if (w < 4) {   // c0 quarter
        const int ot = 4 * s + w;
        f32x4 D = {0.f, 0.f, 0.f, 0.f};
#pragma unroll
        for (int ch = 0; ch < 2; ++ch) {
            bf16x8 bb = *(const bf16x8*)(Wu0f + ((ot * 2 + ch) * 64 + lane) * 8);
            D = __builtin_amdgcn_mfma_f32_16x16x32_bf16(a1[ch], bb, D, 0, 0, 0);
        }
        const float bv = b0[ot * 16 + c];
#pragma unroll
        for (int r = 0; r < 4; ++r)
            c0q[4 * q + r][w * 16 + c] = (__bf16)(D[r] + bv);
    } else if (w == 4) {   // gy0
        const float* rp = Wyu0 + (c & 7) * 64;
        f32x4 D = {0.f, 0.f, 0.f, 0.f};
#pragma unroll
        for (int ch = 0; ch < 2; ++ch) {
            bf16x8 bb = ld_cvt8(rp + ch * 32 + q * 8);
            D = __builtin_amdgcn_mfma_f32_16x16x32_bf16(a1[ch], bb, D, 0, 0, 0);
        }
        if (c < 8) {
            const float bv = byu0[c];
#pragma unroll
            for (int r = 0; r < 4; ++r)
                gy0s[4 * q + r][c] = D[r] + bv;
        }
    }
    __syncthreads();

    // ======== Phase B: level 2 (K=256 over u1) ========
    bf16x8 aF[8];
#pragma unroll
    for (int ch = 0; ch < 8; ++ch)
        aF[ch] = *(const bf16x8*)&u1b[c][ch * 32 + q * 8];

    for (int tt = w; tt < 16; tt += 8) {   // u2 full
        f32x4 D = {0.f, 0.f, 0.f, 0.f};
#pragma unroll
        for (int ch = 0; ch < 8; ++ch) {
            bf16x8 bb = *(const bf16x8*)(Wt1f + ((tt * 8 + ch) * 64 + lane) * 8);
            D = __builtin_amdgcn_mfma_f32_16x16x32_bf16(aF[ch], bb, D, 0, 0, 0);
        }
        const float bv = bt1[tt * 16 + c];
#pragma unroll
        for (int r = 0; r < 4; ++r)
            u2b[4 * q + r][tt * 16 + c] = (__bf16)fmaxf(D[r] + bv, 0.f);
    }
    if (w < 4) {   // gz1 quarter -> global
        const int ot = 4 * s + w, col = ot * 16 + c;
        f32x4 D = {0.f, 0.f, 0.f, 0.f};
#pragma unroll
        for (int ch = 0; ch < 8; ++ch) {
            bf16x8 bb = *(const bf16x8*)(Wzu1f + ((ot * 8 + ch) * 64 + lane) * 8);
            D = __builtin_amdgcn_mfma_f32_16x16x32_bf16(aF[ch], bb, D, 0, 0, 0);
        }
        const float bv = bzu1[col];
#pragma unroll
        for (int r = 0; r < 4; ++r)
            ws[WS_GZ1 + (nb + 4 * q + r) * 256 + col] = fmaxf(D[r] + bv, 0.f);
    } else {       // c1 quarter -> LDS
        const int ot = 4 * s + (w - 4);
        f32x4 D = {0.f, 0.f, 0.f, 0.f};
#pragma unroll
        for (int ch = 0; ch < 8; ++ch) {
            bf16x8 bb = *(const bf16x8*)(Wu1f + ((ot * 8 + ch) * 64 + lane) * 8);
            D = __builtin_amdgcn_mfma_f32_16x16x32_bf16(aF[ch], bb, D, 0, 0, 0);
        }
        const float bv = b1[ot * 16 + c];
#pragma unroll
        for (int r = 0; r < 4; ++r)
            c1q[4 * q + r][(w - 4) * 16 + c] = (__bf16)(D[r] + bv);
    }
    if (w == 0) {  // gy1
        const float* rp = Wyu1 + (c & 7) * 256;
        f32x4 D = {0.f, 0.f, 0.f, 0.f};
#pragma unroll
        for (int ch = 0; ch < 8; ++ch) {
            bf16x8 bb = ld_cvt8(rp + ch * 32 + q * 8);
            D = __builtin_amdgcn_mfma_f32_16x16x32_bf16(aF[ch], bb, D, 0, 0, 0);
        }
        if (c < 8) {
            const float bv = byu1[c];
#pragma unroll
            for (int r = 0; r < 4; ++r)
                gy1s[4 * q + r][c] = D[r] + bv;
        }
    }
    __syncthreads();

    // ======== Phase C: level 3 (K=256 over u2) + yv/cu2 + B2/BX ========
    bf16x8 aG[8];
#pragma unroll
    for (int ch = 0; ch < 8; ++ch)
        aG[ch] = *(const bf16x8*)&u2b[c][ch * 32 + q * 8];

    if (w < 4) {   // w2 quarter -> global
        const int ot = 4 * s + w, col = ot * 16 + c;
        f32x4 D = {0.f, 0.f, 0.f, 0.f};
#pragma unroll
        for (int ch = 0; ch < 8; ++ch) {
            bf16x8 bb = *(const bf16x8*)(Wzu2f + ((ot * 8 + ch) * 64 + lane) * 8);
            D = __builtin_amdgcn_mfma_f32_16x16x32_bf16(aG[ch], bb, D, 0, 0, 0);
        }
        const float bv = bzu2[col];
        const float sp = softplusf(Wz2[col]);
#pragma unroll
        for (int r = 0; r < 4; ++r) {
            float gz2 = fmaxf(D[r] + bv, 0.f);
            ws[WS_W2 + (nb + 4 * q + r) * 256 + col] = gz2 * sp;
        }
    } else if (w == 4 && s == 0) {   // yv (c<8) / cu2 (c==8)
        const float* rp = (c < 8) ? (Wyu2 + c * 256) : Wu2;
        f32x4 D = {0.f, 0.f, 0.f, 0.f};
#pragma unroll
        for (int ch = 0; ch < 8; ++ch) {
            bf16x8 bb = ld_cvt8(rp + ch * 32 + q * 8);
            D = __builtin_amdgcn_mfma_f32_16x16x32_bf16(aG[ch], bb, D, 0, 0, 0);
        }
        if (c < 8) {
            const float bv = byu2[c];
            const float wy2 = Wy2[c];
#pragma unroll
            for (int r = 0; r < 4; ++r) {
                const int n = nb + 4 * q + r;
                ws[WS_YV + n * 8 + c] = Y[n * 8 + c] - (D[r] + bv) * wy2;
            }
        } else if (c == 8) {
#pragma unroll
            for (int r = 0; r < 4; ++r)
                ws[WS_CU2 + nb + 4 * q + r] = D[r] + b2[0];
        }
    }

    // B2/BX materialization for this block's (n-group, z-quarter)
    {
        bf16x8 zz;
#pragma unroll
        for (int j = 0; j < 8; ++j) zz[j] = (__bf16)0.f;
#pragma unroll
        for (int j = 0; j < 2; ++j) {
            const int idx = j * 512 + t;
            const int zl = idx & 63, nl = idx >> 6;
            const int z = 64 * s + zl, n = nb + nl;
            {   // B2
                const float* wy = Wy0 + z * 8;
                __bf16* dst = (__bf16*)(ws + WS_B2) + (n * 256 + z) * 32;
                bf16x8 v0, v1 = zz;
#pragma unroll
                for (int d = 0; d < 8; ++d) v0[d] = (__bf16)(gy0s[nl][d] * wy[d]);
                v1[0] = c0q[nl][zl];
                *(bf16x8*)(dst)      = v0;
                *(bf16x8*)(dst + 8)  = v1;
                *(bf16x8*)(dst + 16) = zz;
                *(bf16x8*)(dst + 24) = zz;
            }
            {   // BX
                const float* wy = Wy1 + z * 8;
                __bf16* dst = (__bf16*)(ws + WS_BX) + (n * 256 + z) * 32;
                bf16x8 v0, v1 = zz;
#pragma unroll
                for (int d = 0; d < 8; ++d) v0[d] = (__bf16)(gy1s[nl][d] * wy[d]);
                v1[0] = c1q[nl][zl];
                *(bf16x8*)(dst)      = v0;
                *(bf16x8*)(dst + 8)  = v1;
                *(bf16x8*)(dst + 16) = zz;
                *(bf16x8*)(dst + 24) = zz;
            }
        }
    }
}

// ---------------------------------------------------------------------------
// k_main: R8 structure (53.6 us proven), half-grid (m_base) x2 launches —
// the R12 configuration that measured the session-best 173.3 us total.
// ---------------------------------------------------------------------------
__global__ __launch_bounds__(256, 4) void k_main(
    const float* __restrict__ U,
    float* __restrict__ ws,
    int m_base)
{
    __shared__ __bf16 zh[64][264];
    __shared__ float gz1s[256];
    __shared__ float w2s[256];
    __shared__ float sdot[64];
    __shared__ float psum[4][64];

    const int t  = threadIdx.x;
    const int n  = blockIdx.y;
    const int m0 = (blockIdx.x + m_base) * 64;
    const int w    = t >> 6;
    const int lane = t & 63;
    const int c = lane & 15;
    const int q = lane >> 4;

    gz1s[t] = ws[WS_GZ1 + n * 256 + t];
    w2s[t]  = ws[WS_W2  + n * 256 + t];
    if (t < 64) {
        float sd = 0.f;
#pragma unroll
        for (int d = 0; d < 8; ++d)
            sd += U[(m0 + t) * 8 + d] * ws[WS_YV + n * 8 + d];
        sdot[t] = sd;
    }

    const __bf16* A2p = (const __bf16*)(ws + WS_A2);
    const __bf16* B2p = (const __bf16*)(ws + WS_B2) + n * 8192;
    const __bf16* BXp = (const __bf16*)(ws + WS_BX) + n * 8192;
    const __bf16* WTF = (const __bf16*)(ws + WS_WTF);

    bf16x8 a2f[4];
#pragma unroll
    for (int mi = 0; mi < 4; ++mi)
        a2f[mi] = *(const bf16x8*)(A2p + (m0 + 16 * mi + c) * 32 + q * 8);

    {
        bf16x8 b2f[4];
#pragma unroll
        for (int zt = 0; zt < 4; ++zt)
            b2f[zt] = *(const bf16x8*)(B2p + (64 * w + 16 * zt + c) * 32 + q * 8);
        f32x4 pre[4][4];
#pragma unroll
        for (int zt = 0; zt < 4; ++zt)
#pragma unroll
            for (int mi = 0; mi < 4; ++mi) {
                f32x4 zacc = {0.f, 0.f, 0.f, 0.f};
                pre[zt][mi] = __builtin_amdgcn_mfma_f32_16x16x32_bf16(
                    b2f[zt], a2f[mi], zacc, 0, 0, 0);
            }
#pragma unroll
        for (int zt = 0; zt < 4; ++zt) {
            const int zb = 64 * w + 16 * zt + 4 * q;
#pragma unroll
            for (int mi = 0; mi < 4; ++mi) {
                bf16x4 v4;
#pragma unroll
                for (int r = 0; r < 4; ++r)
                    v4[r] = (__bf16)(fmaxf(pre[zt][mi][r], 0.f) * gz1s[zb + r]);
                *(bf16x4*)&zh[c + 16 * mi][zb] = v4;
            }
        }
    }

    f32x4 acc[4][4];
#pragma unroll
    for (int mi = 0; mi < 4; ++mi)
#pragma unroll
        for (int kj = 0; kj < 4; ++kj)
            acc[mi][kj] = f32x4{0.f, 0.f, 0.f, 0.f};

    __syncthreads();

    for (int ch = 0; ch < 8; ++ch) {
        bf16x8 az[4], bw[4];
#pragma unroll
        for (int mi = 0; mi < 4; ++mi)
            az[mi] = *(const bf16x8*)&zh[c + 16 * mi][ch * 32 + q * 8];
#pragma unroll
        for (int kj = 0; kj < 4; ++kj)
            bw[kj] = *(const bf16x8*)(WTF + ((4 * w + kj) * 8 + ch) * 512 + lane * 8);
#pragma unroll
        for (int mi = 0; mi < 4; ++mi)
#pragma unroll
            for (int kj = 0; kj < 4; ++kj)
                acc[mi][kj] = __builtin_amdgcn_mfma_f32_16x16x32_bf16(
                    az[mi], bw[kj], acc[mi][kj], 0, 0, 0);
    }
    {
        bf16x8 bx[4];
#pragma unroll
        for (int kj = 0; kj < 4; ++kj)
            bx[kj] = *(const bf16x8*)(BXp + (64 * w + 16 * kj + c) * 32 + q * 8);
#pragma unroll
        for (int mi = 0; mi < 4; ++mi)
#pragma unroll
            for (int kj = 0; kj < 4; ++kj)
                acc[mi][kj] = __builtin_amdgcn_mfma_f32_16x16x32_bf16(
                    a2f[mi], bx[kj], acc[mi][kj], 0, 0, 0);
    }

    float p[4][4];
#pragma unroll
    for (int mi = 0; mi < 4; ++mi)
#pragma unroll
        for (int r = 0; r < 4; ++r) p[mi][r] = 0.f;
#pragma unroll
    for (int kj = 0; kj < 4; ++kj) {
        float w2v = w2s[64 * w + 16 * kj + c];
#pragma unroll
        for (int mi = 0; mi < 4; ++mi)
#pragma unroll
            for (int r = 0; r < 4; ++r)
                p[mi][r] += fmaxf(acc[mi][kj][r], 0.f) * w2v;
    }
#pragma unroll
    for (int mi = 0; mi < 4; ++mi)
#pragma unroll
        for (int r = 0; r < 4; ++r) {
            float v = p[mi][r];
            v += __shfl_xor(v, 8);
            v += __shfl_xor(v, 4);
            v += __shfl_xor(v, 2);
            v += __shfl_xor(v, 1);
            p[mi][r] = v;
        }
    if (c == 0) {
#pragma unroll
        for (int mi = 0; mi < 4; ++mi)
            *(float4*)&psum[w][16 * mi + 4 * q] =
                make_float4(p[mi][0], p[mi][1], p[mi][2], p[mi][3]);
    }
    __syncthreads();
    if (t < 64) {
        float cu2 = ws[WS_CU2 + n];
        float pp = psum[0][t] + psum[1][t] + psum[2][t] + psum[3][t];
        ws[WS_SLACK + n * 2048 + m0 + t] = sdot[t] - cu2 - pp;
    }
}

// ---------------------------------------------------------------------------
// k_lse: per-n stable logsumexp over m -> psi[n]
// ---------------------------------------------------------------------------
__global__ __launch_bounds__(256) void k_lse(const float* __restrict__ ws,
                                             float* __restrict__ out) {
    __shared__ float redmax[4];
    __shared__ float redsum[4];
    const int n = blockIdx.x;
    const int t = threadIdx.x;
    const float* s = ws + WS_SLACK + n * 2048;

    float vals[8];
    float mx = -3.4e38f;
#pragma unroll
    for (int i = 0; i < 8; ++i) {
        vals[i] = s[t + 256 * i];
        mx = fmaxf(mx, vals[i]);
    }
#pragma unroll
    for (int off = 32; off; off >>= 1) mx = fmaxf(mx, __shfl_xor(mx, off));
    if ((t & 63) == 0) redmax[t >> 6] = mx;
    __syncthreads();
    mx = fmaxf(fmaxf(redmax[0], redmax[1]), fmaxf(redmax[2], redmax[3]));

    float sum = 0.f;
#pragma unroll
    for (int i = 0; i < 8; ++i) sum += expf((vals[i] - mx) * (1.f / EPSF));
#pragma unroll
    for (int off = 32; off; off >>= 1) sum += __shfl_xor(sum, off);
    if ((t & 63) == 0) redsum[t >> 6] = sum;
    __syncthreads();
    if (t == 0) {
        float S = redsum[0] + redsum[1] + redsum[2] + redsum[3];
        out[n] = EPSF * logf(S * (1.f / 2048.f)) + mx;
    }
}

// ---------------------------------------------------------------------------
extern "C" void kernel_launch(void* const* d_in, const int* in_sizes, int n_in,
                              void* d_out, int out_size, void* d_ws, size_t ws_size,
                              hipStream_t stream) {
    const float* X    = (const float*)d_in[0];
    const float* Uu   = (const float*)d_in[1];
    const float* Yy   = (const float*)d_in[2];
    const float* Wt0  = (const float*)d_in[3];
    const float* bt0  = (const float*)d_in[4];
    const float* Wt1  = (const float*)d_in[5];
    const float* bt1  = (const float*)d_in[6];
    const float* Wyu0 = (const float*)d_in[7];
    const float* byu0 = (const float*)d_in[8];
    const float* Wy0  = (const float*)d_in[9];
    const float* Wu0  = (const float*)d_in[10];
    const float* b0   = (const float*)d_in[11];
    const float* Wzu1 = (const float*)d_in[12];
    const float* bzu1 = (const float*)d_in[13];
    const float* Wz1  = (const float*)d_in[14];
    const float* Wyu1 = (const float*)d_in[15];
    const float* byu1 = (const float*)d_in[16];
    const float* Wy1  = (const float*)d_in[17];
    const float* Wu1  = (const float*)d_in[18];
    const float* b1   = (const float*)d_in[19];
    const float* Wzu2 = (const float*)d_in[20];
    const float* bzu2 = (const float*)d_in[21];
    const float* Wz2  = (const float*)d_in[22];
    const float* Wyu2 = (const float*)d_in[23];
    const float* byu2 = (const float*)d_in[24];
    const float* Wy2  = (const float*)d_in[25];
    const float* Wu2  = (const float*)d_in[26];
    const float* b2   = (const float*)d_in[27];
    float* ws  = (float*)d_ws;
    float* out = (float*)d_out;

    k_wprep<<<dim3(424), dim3(256), 0, stream>>>(
        X, Uu, Wt0, Wu0, Wt1, Wzu1, Wu1, Wzu2, Wz1, ws);
    k_ctx<<<dim3(32), dim3(512), 0, stream>>>(
        Yy, bt0, b0, Wyu0, byu0, Wy0, bt1, bzu1, Wyu1, byu1, Wy1, b1,
        bzu2, Wz2, Wyu2, byu2, Wy2, Wu2, b2, ws);
    k_main<<<dim3(16, NN), dim3(256), 0, stream>>>(Uu, ws, 0);
    k_main<<<dim3(16, NN), dim3(256), 0, stream>>>(Uu, ws, 16);
    k_lse<<<dim3(128), dim3(256), 0, stream>>>(ws, out);
}